// Round 1
// baseline (424.971 us; speedup 1.0000x reference)
//
#include <hip/hip_runtime.h>

// Haar DWT LEVEL=1 on x:(32, 4096, 512) fp32.
// out[:, 0:2048, :]    = (x[:, 0::2, :] + x[:, 1::2, :]) * 1/sqrt(2)
// out[:, 2048:4096, :] = (x[:, 0::2, :] - x[:, 1::2, :]) * 1/sqrt(2)
//
// Memory-bound: 256 MiB in + 256 MiB out. One thread per float4.

#define B_    32
#define L_    4096
#define HALF_ 2048
#define F4_   128   // 512 floats / 4 per float4

__global__ __launch_bounds__(256) void haar_dwt1(const float4* __restrict__ x,
                                                 float4* __restrict__ out) {
    const float inv_sqrt2 = 0.70710678118654752440f;
    int tid = blockIdx.x * 256 + threadIdx.x;      // [0, 32*2048*128) = [0, 8388608)
    int f4 = tid & (F4_ - 1);                      // which float4 within the 512-float row
    int p  = tid >> 7;                             // pair index: b*2048 + i
    int i  = p & (HALF_ - 1);
    int b  = p >> 11;

    int in_off = (b * L_ + 2 * i) * F4_ + f4;      // max 16,777,216 < 2^31 — int ok
    float4 x0 = x[in_off];
    float4 x1 = x[in_off + F4_];                   // next row, +2048 bytes

    float4 cA, cD;
    cA.x = (x0.x + x1.x) * inv_sqrt2;
    cA.y = (x0.y + x1.y) * inv_sqrt2;
    cA.z = (x0.z + x1.z) * inv_sqrt2;
    cA.w = (x0.w + x1.w) * inv_sqrt2;
    cD.x = (x0.x - x1.x) * inv_sqrt2;
    cD.y = (x0.y - x1.y) * inv_sqrt2;
    cD.z = (x0.z - x1.z) * inv_sqrt2;
    cD.w = (x0.w - x1.w) * inv_sqrt2;

    out[(b * L_ + i) * F4_ + f4]         = cA;
    out[(b * L_ + HALF_ + i) * F4_ + f4] = cD;
}

extern "C" void kernel_launch(void* const* d_in, const int* in_sizes, int n_in,
                              void* d_out, int out_size, void* d_ws, size_t ws_size,
                              hipStream_t stream) {
    const float4* x = (const float4*)d_in[0];
    float4* out = (float4*)d_out;
    // total float4 units = 32*2048*128 = 8,388,608 -> 32768 blocks of 256
    int n4 = B_ * HALF_ * F4_;
    haar_dwt1<<<n4 / 256, 256, 0, stream>>>(x, out);
}

// Round 3
// 412.480 us; speedup vs baseline: 1.0303x; 1.0303x over previous
//
#include <hip/hip_runtime.h>

// Haar DWT LEVEL=1 on x:(32, 4096, 512) fp32.
// out[:, 0:2048, :]    = (x[:, 0::2, :] + x[:, 1::2, :]) * 1/sqrt(2)
// out[:, 2048:4096, :] = (x[:, 0::2, :] - x[:, 1::2, :]) * 1/sqrt(2)
//
// Pure streaming: 256 MiB in + 256 MiB out, zero reuse.
// Non-temporal loads/stores to avoid polluting the 32 MiB L2.

#define B_    32
#define L_    4096
#define HALF_ 2048
#define F4_   128   // 512 floats / 4 per vec4

typedef float v4 __attribute__((ext_vector_type(4)));

__global__ __launch_bounds__(256) void haar_dwt1(const v4* __restrict__ x,
                                                 v4* __restrict__ out) {
    const float inv_sqrt2 = 0.70710678118654752440f;
    unsigned tid = blockIdx.x * 256u + threadIdx.x;   // [0, 32*2048*128)
    unsigned f4 = tid & (F4_ - 1);                    // vec4 index within 512-float row
    unsigned p  = tid >> 7;                           // pair index: b*2048 + i
    unsigned i  = p & (HALF_ - 1);
    unsigned b  = p >> 11;

    unsigned in_off = (b * L_ + 2u * i) * F4_ + f4;
    v4 x0 = __builtin_nontemporal_load(x + in_off);
    v4 x1 = __builtin_nontemporal_load(x + in_off + F4_);

    v4 cA = (x0 + x1) * inv_sqrt2;
    v4 cD = (x0 - x1) * inv_sqrt2;

    __builtin_nontemporal_store(cA, out + (b * L_ + i) * F4_ + f4);
    __builtin_nontemporal_store(cD, out + (b * L_ + HALF_ + i) * F4_ + f4);
}

extern "C" void kernel_launch(void* const* d_in, const int* in_sizes, int n_in,
                              void* d_out, int out_size, void* d_ws, size_t ws_size,
                              hipStream_t stream) {
    const v4* x = (const v4*)d_in[0];
    v4* out = (v4*)d_out;
    // total vec4 units = 32*2048*128 = 8,388,608 -> 32768 blocks of 256
    int n4 = B_ * HALF_ * F4_;
    haar_dwt1<<<n4 / 256, 256, 0, stream>>>(x, out);
}